// Round 1
// baseline (361.597 us; speedup 1.0000x reference)
//
#include <hip/hip_runtime.h>
#include <hip/hip_bf16.h>

// ---------- types & helpers ----------
typedef __attribute__((ext_vector_type(4))) float  f32x4;
typedef __attribute__((ext_vector_type(8))) __bf16 bf16x8;
typedef __attribute__((ext_vector_type(8))) unsigned short u16x8;

typedef const __attribute__((address_space(1))) void gas_void;
typedef __attribute__((address_space(3))) void las_void;

__device__ __forceinline__ unsigned short f2bf(float x) {
    unsigned u = __builtin_bit_cast(unsigned, x);
    u += 0x7fffu + ((u >> 16) & 1u);          // round-to-nearest-even
    return (unsigned short)(u >> 16);
}
__device__ __forceinline__ float bf2f(unsigned short h) {
    unsigned u = ((unsigned)h) << 16;
    return __builtin_bit_cast(float, u);
}
__device__ __forceinline__ void gload_lds16(const void* g, void* l) {
    __builtin_amdgcn_global_load_lds((gas_void*)g, (las_void*)l, 16, 0, 0);
}

// ---------- kernel 1: fp32 -> bf16 convert (vectorized) ----------
__global__ void k_f32_to_bf16(const float* __restrict__ in,
                              unsigned short* __restrict__ out, int n4) {
    int i = blockIdx.x * blockDim.x + threadIdx.x;
    if (i < n4) {
        float4 v = ((const float4*)in)[i];
        ushort4 o;
        o.x = f2bf(v.x); o.y = f2bf(v.y); o.z = f2bf(v.z); o.w = f2bf(v.w);
        ((ushort4*)out)[i] = o;
    }
}

// ---------- kernel 2: W [K=1024][N=3072] fp32 -> Wt [N][K] bf16 ----------
__global__ void k_transpose_w(const float* __restrict__ W,
                              unsigned short* __restrict__ Wt,
                              int K, int N) {
    __shared__ unsigned short tile[32][33];
    int n0 = blockIdx.x * 32, k0 = blockIdx.y * 32;
    int tx = threadIdx.x, ty = threadIdx.y;   // 32 x 8
#pragma unroll
    for (int i = 0; i < 4; i++) {
        int kk = ty + i * 8;
        tile[kk][tx] = f2bf(W[(size_t)(k0 + kk) * N + n0 + tx]);
    }
    __syncthreads();
#pragma unroll
    for (int i = 0; i < 4; i++) {
        int nn = ty + i * 8;
        Wt[(size_t)(n0 + nn) * K + k0 + tx] = tile[tx][nn];
    }
}

// ---------- kernel 3: V slice of qkv -> Vt [b][D=1024][S=4096] bf16 ----------
__global__ void k_transpose_v(const unsigned short* __restrict__ qkv,
                              unsigned short* __restrict__ Vt) {
    __shared__ unsigned short tile[32][33];
    int b = blockIdx.z;
    int s0 = blockIdx.x * 32, d0 = blockIdx.y * 32;
    int tx = threadIdx.x, ty = threadIdx.y;   // 32 x 8
#pragma unroll
    for (int i = 0; i < 4; i++) {
        int ss = ty + i * 8;
        tile[ss][tx] = qkv[((size_t)(b * 4096 + s0 + ss)) * 3072 + 2048 + d0 + tx];
    }
    __syncthreads();
#pragma unroll
    for (int i = 0; i < 4; i++) {
        int dd = ty + i * 8;
        Vt[((size_t)b * 1024 + d0 + dd) * 4096 + s0 + tx] = tile[tx][dd];
    }
}

// ---------- GEMM: C[M,N] = alpha * A[M,K] * Bt[N,K]^T (+ bias) ----------
// m97-style: 128x128 tile, BK=32, 4 waves (2x2 of 64x64), global_load_lds w=16,
// mfma_f32_16x16x32_bf16.  A,Bt bf16; C fp32 or bf16.
template <bool OUT_BF16, bool BIAS>
__global__ void k_gemm_bt(const unsigned short* __restrict__ A, int lda,
                          const unsigned short* __restrict__ Bt, int ldb,
                          void* __restrict__ C, int ldc,
                          const float* __restrict__ bias,
                          int M, int N, int K, float alpha) {
    __shared__ __align__(16) unsigned short As[128 * 32];
    __shared__ __align__(16) unsigned short Bs[128 * 32];

    const int tid  = threadIdx.x;
    const int lane = tid & 63;
    const int w    = tid >> 6;         // 0..3
    const int wr   = w >> 1, wc = w & 1;
    const int m0   = blockIdx.y * 128;
    const int n0   = blockIdx.x * 128;

    f32x4 acc[4][4] = {};

    const int r0  = lane >> 2;         // 0..15 (row within 16-row stripe)
    const int cEl = (lane & 3) * 8;    // k element offset 0/8/16/24

    for (int k0 = 0; k0 < K; k0 += 32) {
        // stage A tile: 8 wave-calls total, this wave does c = w and c = w+4
#pragma unroll
        for (int i = 0; i < 2; i++) {
            const int c   = w + 4 * i;
            const int row = c * 16 + r0;
            gload_lds16(A + (size_t)(m0 + row) * lda + k0 + cEl,
                        (void*)(As + c * 512));
        }
#pragma unroll
        for (int i = 0; i < 2; i++) {
            const int c   = w + 4 * i;
            const int row = c * 16 + r0;
            gload_lds16(Bt + (size_t)(n0 + row) * ldb + k0 + cEl,
                        (void*)(Bs + c * 512));
        }
        __syncthreads();   // drains vmcnt; LDS tiles ready

        bf16x8 af[4], bfr[4];
#pragma unroll
        for (int m = 0; m < 4; m++)
            af[m] = *(const bf16x8*)&As[(wr * 64 + m * 16 + (lane & 15)) * 32 + (lane >> 4) * 8];
#pragma unroll
        for (int n = 0; n < 4; n++)
            bfr[n] = *(const bf16x8*)&Bs[(wc * 64 + n * 16 + (lane & 15)) * 32 + (lane >> 4) * 8];

#pragma unroll
        for (int m = 0; m < 4; m++)
#pragma unroll
            for (int n = 0; n < 4; n++)
                acc[m][n] = __builtin_amdgcn_mfma_f32_16x16x32_bf16(af[m], bfr[n], acc[m][n], 0, 0, 0);

        __syncthreads();   // protect LDS before next-stage overwrite
    }

    // epilogue: C/D layout col = lane&15, row = (lane>>4)*4 + r
#pragma unroll
    for (int m = 0; m < 4; m++) {
        const int row = m0 + wr * 64 + m * 16 + (lane >> 4) * 4;
#pragma unroll
        for (int n = 0; n < 4; n++) {
            const int col = n0 + wc * 64 + n * 16 + (lane & 15);
            const float bv = BIAS ? bias[col] : 0.0f;
#pragma unroll
            for (int r = 0; r < 4; r++) {
                const float v = acc[m][n][r] * alpha + bv;
                if (OUT_BF16)
                    ((unsigned short*)C)[(size_t)(row + r) * ldc + col] = f2bf(v);
                else
                    ((float*)C)[(size_t)(row + r) * ldc + col] = v;
            }
        }
    }
}

// ---------- in-place row softmax on bf16 scores [rows][S=4096] ----------
__global__ __launch_bounds__(256) void k_softmax_inplace(unsigned short* __restrict__ P, int S) {
    __shared__ float red[8];
    const int row  = blockIdx.x;
    const int tid  = threadIdx.x;
    const int lane = tid & 63;
    const int wid  = tid >> 6;
    unsigned short* p = P + (size_t)row * S;

    float v[16];
    u16x8 h0 = *(const u16x8*)&p[tid * 16];
    u16x8 h1 = *(const u16x8*)&p[tid * 16 + 8];
    float mx = -1e30f;
#pragma unroll
    for (int j = 0; j < 8; j++) { v[j]     = bf2f(h0[j]); mx = fmaxf(mx, v[j]);     }
#pragma unroll
    for (int j = 0; j < 8; j++) { v[j + 8] = bf2f(h1[j]); mx = fmaxf(mx, v[j + 8]); }

#pragma unroll
    for (int o = 32; o >= 1; o >>= 1) mx = fmaxf(mx, __shfl_xor(mx, o));
    if (lane == 0) red[wid] = mx;
    __syncthreads();
    mx = fmaxf(fmaxf(red[0], red[1]), fmaxf(red[2], red[3]));

    float sum = 0.0f;
#pragma unroll
    for (int j = 0; j < 16; j++) { v[j] = __expf(v[j] - mx); sum += v[j]; }
#pragma unroll
    for (int o = 32; o >= 1; o >>= 1) sum += __shfl_xor(sum, o);
    if (lane == 0) red[4 + wid] = sum;
    __syncthreads();
    sum = red[4] + red[5] + red[6] + red[7];
    const float rinv = 1.0f / sum;

    u16x8 o0, o1;
#pragma unroll
    for (int j = 0; j < 8; j++) { o0[j] = f2bf(v[j] * rinv); o1[j] = f2bf(v[j + 8] * rinv); }
    *(u16x8*)&p[tid * 16]     = o0;
    *(u16x8*)&p[tid * 16 + 8] = o1;
}

// ---------- launch ----------
extern "C" void kernel_launch(void* const* d_in, const int* in_sizes, int n_in,
                              void* d_out, int out_size, void* d_ws, size_t ws_size,
                              hipStream_t stream) {
    const float* x    = (const float*)d_in[0];   // [2,4096,1024]
    const float* W    = (const float*)d_in[1];   // [1024,3072]
    const float* bias = (const float*)d_in[2];   // [3072]
    float* out        = (float*)d_out;           // [2,4096,1024]

    char* ws = (char*)d_ws;
    unsigned short* xb  = (unsigned short*)(ws);                 // 8192*1024 bf16  (16 MB)
    unsigned short* Wt  = (unsigned short*)(ws + 16777216);      // 3072*1024 bf16  ( 6 MB)
    unsigned short* qkv = (unsigned short*)(ws + 23068672);      // 8192*3072 bf16  (50 MB)
    unsigned short* Vt  = (unsigned short*)(ws + 73400320);      // 2*1024*4096 bf16(16 MB)
    unsigned short* P   = (unsigned short*)(ws + 90177536);      // 4096*4096 bf16  (32 MB, reused)

    // 1. x -> bf16
    k_f32_to_bf16<<<8192, 256, 0, stream>>>(x, xb, (8192 * 1024) / 4);
    // 2. W -> Wt (bf16, transposed)
    k_transpose_w<<<dim3(96, 32), dim3(32, 8), 0, stream>>>(W, Wt, 1024, 3072);
    // 3. qkv = x*W + b   (M=8192, N=3072, K=1024)
    k_gemm_bt<true, true><<<dim3(24, 64), 256, 0, stream>>>(
        xb, 1024, Wt, 1024, (void*)qkv, 3072, bias, 8192, 3072, 1024, 1.0f);
    // 4. V -> Vt
    k_transpose_v<<<dim3(128, 32, 2), dim3(32, 8), 0, stream>>>(qkv, Vt);

    const float scale = 0.03125f;  // 1/sqrt(1024)
    for (int b = 0; b < 2; b++) {
        const unsigned short* Q  = qkv + (size_t)b * 4096 * 3072;
        const unsigned short* Kp = Q + 1024;
        // scores = Q*K^T * scale  (M=N=4096, K=1024) -> bf16
        k_gemm_bt<true, false><<<dim3(32, 32), 256, 0, stream>>>(
            Q, 3072, Kp, 3072, (void*)P, 4096, nullptr, 4096, 4096, 1024, scale);
        // row softmax in place
        k_softmax_inplace<<<4096, 256, 0, stream>>>(P, 4096);
        // out_b = P * V   (M=4096, N=1024, K=4096) -> fp32
        k_gemm_bt<false, false><<<dim3(8, 32), 256, 0, stream>>>(
            P, 4096, Vt + (size_t)b * 1024 * 4096, 4096,
            (void*)(out + (size_t)b * 4096 * 1024), 1024, nullptr, 4096, 1024, 4096, 1.0f);
    }
}

// Round 2
// 302.597 us; speedup vs baseline: 1.1950x; 1.1950x over previous
//
#include <hip/hip_runtime.h>
#include <hip/hip_bf16.h>

// ---------- types & helpers ----------
typedef __attribute__((ext_vector_type(4))) float  f32x4;
typedef __attribute__((ext_vector_type(8))) __bf16 bf16x8;
typedef __attribute__((ext_vector_type(8))) unsigned short u16x8;

typedef const __attribute__((address_space(1))) void gas_void;
typedef __attribute__((address_space(3))) void las_void;

__device__ __forceinline__ unsigned short f2bf(float x) {
    unsigned u = __builtin_bit_cast(unsigned, x);
    u += 0x7fffu + ((u >> 16) & 1u);          // round-to-nearest-even
    return (unsigned short)(u >> 16);
}
__device__ __forceinline__ float bf2f(unsigned short h) {
    unsigned u = ((unsigned)h) << 16;
    return __builtin_bit_cast(float, u);
}
__device__ __forceinline__ void gload_lds16(const void* g, void* l) {
    __builtin_amdgcn_global_load_lds((gas_void*)g, (las_void*)l, 16, 0, 0);
}

// ---------- kernel 1: fp32 -> bf16 convert (vectorized) ----------
__global__ void k_f32_to_bf16(const float* __restrict__ in,
                              unsigned short* __restrict__ out, int n4) {
    int i = blockIdx.x * blockDim.x + threadIdx.x;
    if (i < n4) {
        float4 v = ((const float4*)in)[i];
        ushort4 o;
        o.x = f2bf(v.x); o.y = f2bf(v.y); o.z = f2bf(v.z); o.w = f2bf(v.w);
        ((ushort4*)out)[i] = o;
    }
}

// ---------- kernel 2: W [K=1024][N=3072] fp32 -> Wt [N][K] bf16 ----------
__global__ void k_transpose_w(const float* __restrict__ W,
                              unsigned short* __restrict__ Wt,
                              int K, int N) {
    __shared__ unsigned short tile[32][33];
    int n0 = blockIdx.x * 32, k0 = blockIdx.y * 32;
    int tx = threadIdx.x, ty = threadIdx.y;   // 32 x 8
#pragma unroll
    for (int i = 0; i < 4; i++) {
        int kk = ty + i * 8;
        tile[kk][tx] = f2bf(W[(size_t)(k0 + kk) * N + n0 + tx]);
    }
    __syncthreads();
#pragma unroll
    for (int i = 0; i < 4; i++) {
        int nn = ty + i * 8;
        Wt[(size_t)(n0 + nn) * K + k0 + tx] = tile[tx][nn];
    }
}

// ---------- kernel 3: Vrow [b][S=4096][D=1024] -> Vt [b][D][S] bf16 ----------
__global__ void k_transpose_v(const unsigned short* __restrict__ Vrow,
                              unsigned short* __restrict__ Vt) {
    __shared__ unsigned short tile[32][33];
    int b = blockIdx.z;
    int s0 = blockIdx.x * 32, d0 = blockIdx.y * 32;
    int tx = threadIdx.x, ty = threadIdx.y;   // 32 x 8
#pragma unroll
    for (int i = 0; i < 4; i++) {
        int ss = ty + i * 8;
        tile[ss][tx] = Vrow[((size_t)(b * 4096 + s0 + ss)) * 1024 + d0 + tx];
    }
    __syncthreads();
#pragma unroll
    for (int i = 0; i < 4; i++) {
        int dd = ty + i * 8;
        Vt[((size_t)b * 1024 + d0 + dd) * 4096 + s0 + tx] = tile[tx][dd];
    }
}

// ---------- GEMM: C[M,N] = alpha * A[M,K] * Bt[N,K]^T (+ bias) ----------
// m97-style: 128x128 tile, BK=32, 4 waves (2x2 of 64x64), global_load_lds w=16,
// mfma_f32_16x16x32_bf16.  A,Bt bf16.
// MODE 0: fp32 C.  MODE 1: bf16 C.  MODE 2: bf16, route cols {Q|K} in C, V in Vp, +bias.
template <int MODE>
__global__ void k_gemm_bt(const unsigned short* __restrict__ A, int lda,
                          const unsigned short* __restrict__ Bt, int ldb,
                          void* __restrict__ C, int ldc,
                          unsigned short* __restrict__ Vp,
                          const float* __restrict__ bias,
                          int K, float alpha,
                          long sA, long sB, long sC) {
    __shared__ __align__(16) unsigned short As[128 * 32];
    __shared__ __align__(16) unsigned short Bs[128 * 32];

    const int z = blockIdx.z;
    A  += (size_t)z * sA;
    Bt += (size_t)z * sB;

    const int tid  = threadIdx.x;
    const int lane = tid & 63;
    const int w    = tid >> 6;         // 0..3
    const int wr   = w >> 1, wc = w & 1;
    const int m0   = blockIdx.y * 128;
    const int n0   = blockIdx.x * 128;

    f32x4 acc[4][4] = {};

    const int r0  = lane >> 2;         // 0..15 (row within 16-row stripe)
    const int cEl = (lane & 3) * 8;    // k element offset 0/8/16/24

    for (int k0 = 0; k0 < K; k0 += 32) {
#pragma unroll
        for (int i = 0; i < 2; i++) {
            const int c   = w + 4 * i;
            const int row = c * 16 + r0;
            gload_lds16(A + (size_t)(m0 + row) * lda + k0 + cEl,
                        (void*)(As + c * 512));
        }
#pragma unroll
        for (int i = 0; i < 2; i++) {
            const int c   = w + 4 * i;
            const int row = c * 16 + r0;
            gload_lds16(Bt + (size_t)(n0 + row) * ldb + k0 + cEl,
                        (void*)(Bs + c * 512));
        }
        __syncthreads();   // drains vmcnt; LDS tiles ready

        bf16x8 af[4], bfr[4];
#pragma unroll
        for (int m = 0; m < 4; m++)
            af[m] = *(const bf16x8*)&As[(wr * 64 + m * 16 + (lane & 15)) * 32 + (lane >> 4) * 8];
#pragma unroll
        for (int n = 0; n < 4; n++)
            bfr[n] = *(const bf16x8*)&Bs[(wc * 64 + n * 16 + (lane & 15)) * 32 + (lane >> 4) * 8];

#pragma unroll
        for (int m = 0; m < 4; m++)
#pragma unroll
            for (int n = 0; n < 4; n++)
                acc[m][n] = __builtin_amdgcn_mfma_f32_16x16x32_bf16(af[m], bfr[n], acc[m][n], 0, 0, 0);

        __syncthreads();   // protect LDS before next-stage overwrite
    }

    // epilogue: C/D layout col = lane&15, row = (lane>>4)*4 + r
#pragma unroll
    for (int m = 0; m < 4; m++) {
        const int row = m0 + wr * 64 + m * 16 + (lane >> 4) * 4;
#pragma unroll
        for (int n = 0; n < 4; n++) {
            const int col = n0 + wc * 64 + n * 16 + (lane & 15);
            const float bv = (MODE == 2) ? bias[col] : 0.0f;
#pragma unroll
            for (int r = 0; r < 4; r++) {
                const float v = acc[m][n][r] * alpha + bv;
                if (MODE == 0) {
                    ((float*)C)[(size_t)z * sC + (size_t)(row + r) * ldc + col] = v;
                } else if (MODE == 1) {
                    ((unsigned short*)C)[(size_t)z * sC + (size_t)(row + r) * ldc + col] = f2bf(v);
                } else {
                    const int lc = col & 1023;
                    if (col < 2048) {
                        // Qb at C, Kb contiguous after it (8192*1024 elems apart)
                        ((unsigned short*)C)[(size_t)(col >> 10) * 8388608 +
                                             (size_t)(row + r) * 1024 + lc] = f2bf(v);
                    } else {
                        Vp[(size_t)(row + r) * 1024 + lc] = f2bf(v);
                    }
                }
            }
        }
    }
}

// ---------- in-place row softmax on bf16 scores [rows][S=4096] ----------
__global__ __launch_bounds__(256) void k_softmax_inplace(unsigned short* __restrict__ P, int S) {
    __shared__ float red[8];
    const int row  = blockIdx.x;
    const int tid  = threadIdx.x;
    const int lane = tid & 63;
    const int wid  = tid >> 6;
    unsigned short* p = P + (size_t)row * S;

    float v[16];
    u16x8 h0 = *(const u16x8*)&p[tid * 16];
    u16x8 h1 = *(const u16x8*)&p[tid * 16 + 8];
    float mx = -1e30f;
#pragma unroll
    for (int j = 0; j < 8; j++) { v[j]     = bf2f(h0[j]); mx = fmaxf(mx, v[j]);     }
#pragma unroll
    for (int j = 0; j < 8; j++) { v[j + 8] = bf2f(h1[j]); mx = fmaxf(mx, v[j + 8]); }

#pragma unroll
    for (int o = 32; o >= 1; o >>= 1) mx = fmaxf(mx, __shfl_xor(mx, o));
    if (lane == 0) red[wid] = mx;
    __syncthreads();
    mx = fmaxf(fmaxf(red[0], red[1]), fmaxf(red[2], red[3]));

    float sum = 0.0f;
#pragma unroll
    for (int j = 0; j < 16; j++) { v[j] = __expf(v[j] - mx); sum += v[j]; }
#pragma unroll
    for (int o = 32; o >= 1; o >>= 1) sum += __shfl_xor(sum, o);
    if (lane == 0) red[4 + wid] = sum;
    __syncthreads();
    sum = red[4] + red[5] + red[6] + red[7];
    const float rinv = 1.0f / sum;

    u16x8 o0, o1;
#pragma unroll
    for (int j = 0; j < 8; j++) { o0[j] = f2bf(v[j] * rinv); o1[j] = f2bf(v[j + 8] * rinv); }
    *(u16x8*)&p[tid * 16]     = o0;
    *(u16x8*)&p[tid * 16 + 8] = o1;
}

// ---------- launch ----------
extern "C" void kernel_launch(void* const* d_in, const int* in_sizes, int n_in,
                              void* d_out, int out_size, void* d_ws, size_t ws_size,
                              hipStream_t stream) {
    const float* x    = (const float*)d_in[0];   // [2,4096,1024]
    const float* W    = (const float*)d_in[1];   // [1024,3072]
    const float* bias = (const float*)d_in[2];   // [3072]
    float* out        = (float*)d_out;           // [2,4096,1024]

    // ws layout (MB):  Qb@0(16)  Kb@16(16)  Vt@32(16)  xb@48(16)  Wt@64(6)  Vrow@70(16)
    // Pcat@48(64) overlays the dead xb/Wt/Vrow after GEMM1+transpose_v.  Peak 112 MB.
    char* ws = (char*)d_ws;
    unsigned short* Qb   = (unsigned short*)(ws);                  // [2,4096,1024] bf16
    unsigned short* Vt   = (unsigned short*)(ws + 33554432);       // [2,1024,4096] bf16
    unsigned short* xb   = (unsigned short*)(ws + 50331648);       // [8192,1024]  bf16
    unsigned short* Wt   = (unsigned short*)(ws + 67108864);       // [3072,1024]  bf16
    unsigned short* Vrow = (unsigned short*)(ws + 73400320);       // [2,4096,1024] bf16
    unsigned short* Pcat = (unsigned short*)(ws + 50331648);       // [2,4096,4096] bf16

    // 1. x -> bf16
    k_f32_to_bf16<<<8192, 256, 0, stream>>>(x, xb, (8192 * 1024) / 4);
    // 2. W -> Wt (bf16, transposed)
    k_transpose_w<<<dim3(96, 32), dim3(32, 8), 0, stream>>>(W, Wt, 1024, 3072);
    // 3. qkv = x*W + b  (M=8192, N=3072, K=1024), routed into Qb|Kb|Vrow
    k_gemm_bt<2><<<dim3(24, 64, 1), 256, 0, stream>>>(
        xb, 1024, Wt, 1024, (void*)Qb, 1024, Vrow, bias, 1024, 1.0f, 0, 0, 0);
    // 4. Vrow -> Vt
    k_transpose_v<<<dim3(128, 32, 2), dim3(32, 8), 0, stream>>>(Vrow, Vt);

    const float scale = 0.03125f;  // 1/sqrt(1024)
    // 5. scores = Q*K^T * scale  (M=N=4096, K=1024, z=2) -> bf16 Pcat
    k_gemm_bt<1><<<dim3(32, 32, 2), 256, 0, stream>>>(
        Qb, 1024, Qb + 8388608, 1024, (void*)Pcat, 4096, nullptr, nullptr,
        1024, scale, 4194304, 4194304, 16777216);
    // 6. row softmax in place (8192 rows)
    k_softmax_inplace<<<8192, 256, 0, stream>>>(Pcat, 4096);
    // 7. out = P * V  (M=4096, N=1024, K=4096, z=2) -> fp32
    k_gemm_bt<0><<<dim3(8, 32, 2), 256, 0, stream>>>(
        Pcat, 4096, Vt, 4096, (void*)out, 1024, nullptr, nullptr,
        4096, 1.0f, 16777216, 4194304, 4194304);
}